// Round 19
// baseline (91.048 us; speedup 1.0000x reference)
//
#include <hip/hip_runtime.h>

// ConvAttention collapse:
//   softmax_j(Aq[i]+Ak[j]+ba) == softmax_j(Ak_linear[j])   (i-terms & biases cancel)
//   out[i] = Wv * (sum_j sm[j] * x[j]) + bv                (identical for all i)
// Pipeline: k_prep -> k_z (1 px/thread, channels in 8-deep load batches ->
//           ILP-pipelined; s_load weights) -> k_ak (tap shift-sum)
//           -> k_xbar (softmax + weighted avg) -> k_mat (matvec + broadcast)

#define HW    9216      // 96*96
#define HDIM  96
#define WDIM  96
#define CDIM  128
#define WP    28        // padded taps per row (16B-aligned rows)

__device__ __forceinline__ void fma4(float4& a, const float4& x, const float4& s) {
    a.x += x.x * s.x; a.y += x.y * s.y; a.z += x.z * s.z; a.w += x.w * s.w;
}
__device__ __forceinline__ void axpy4(float4& o, float w, const float4& v) {
    o.x += w * v.x; o.y += w * v.y; o.z += w * v.z; o.w += w * v.w;
}

// ---------------- K0: prep — weffp padded (blocks 0..13) + Wv^T (14..77) --
// weffp[c'][tap] = sum_c Wk[c][c'] * Wa[(128+c)][tap], rows padded to 28.
__global__ void k_prep(const float* __restrict__ Wk, const float* __restrict__ Wa,
                       const float* __restrict__ Wv,
                       float* __restrict__ weffp, float* __restrict__ wvt) {
    const int b = blockIdx.x;
    if (b < 14) {
        int idx = b * 256 + threadIdx.x;
        if (idx < 128 * WP) {
            int cp = idx / WP, tap = idx % WP;
            float s = 0.f;
            if (tap < 25)
                for (int c = 0; c < 128; ++c)
                    s += Wk[c * 128 + cp] * Wa[(128 + c) * 25 + tap];
            weffp[idx] = s;
        }
    } else {
        int idx = (b - 14) * 256 + threadIdx.x;        // 0..16383
        wvt[(idx & 127) * 128 + (idx >> 7)] = Wv[idx]; // wvt[c'][c] = Wv[c][c']
    }
}

// ---------------- K1: z[j][t][px] = sum_c weff[c][t] * x[j][c][px] ---------
// 1 px/thread, all 128 channels. The c-loop is hand-pipelined in batches of
// 8: issue 8 INDEPENDENT coalesced loads (one vmcnt wait per batch), then
// 8x25 fmacs with wave-uniform s_load weights. Breaks round-18's serial
// load->wait->fma chain (VGPR was 32 -> loop rolled; now ~42 with xv[8]).
__global__ __launch_bounds__(256) void k_z(const float* __restrict__ x,
                                           const float* __restrict__ weffp,
                                           float* __restrict__ z) {
    const int j  = blockIdx.y;
    const int px = blockIdx.x * 256 + threadIdx.x;
    const float* xb = x + (size_t)j * CDIM * HW + px;

    float acc[25];
    #pragma unroll
    for (int t = 0; t < 25; ++t) acc[t] = 0.f;

    for (int cb = 0; cb < 128; cb += 8) {
        float xv[8];
        #pragma unroll
        for (int u = 0; u < 8; ++u)
            xv[u] = xb[(size_t)(cb + u) * HW];     // 8 loads in flight
        #pragma unroll
        for (int u = 0; u < 8; ++u) {
            const float* wr = weffp + (cb + u) * WP;   // uniform -> s_load
            #pragma unroll
            for (int t = 0; t < 25; ++t)
                acc[t] = fmaf(wr[t], xv[u], acc[t]);
        }
    }

    float* zb = z + (size_t)j * 25 * HW + px;
    #pragma unroll
    for (int t = 0; t < 25; ++t) zb[(size_t)t * HW] = acc[t];
}

// ---------------- K2: ak[j][px..px+3] via aligned 3-quad windows -----------
__global__ __launch_bounds__(256) void k_ak(const float* __restrict__ z,
                                            float* __restrict__ ak) {
    const int j  = blockIdx.y;
    const int px = (blockIdx.x * 256 + threadIdx.x) * 4;
    const int h  = px / WDIM, cb = px % WDIM;
    const bool cok0 = (cb > 0);
    const bool cok2 = (cb < WDIM - 4);
    const float4 zf = make_float4(0.f, 0.f, 0.f, 0.f);
    const float* zb = z + (size_t)j * 25 * HW + px;

    float s0 = 0.f, s1 = 0.f, s2 = 0.f, s3 = 0.f;
    #pragma unroll
    for (int kh = 0; kh < 5; ++kh) {
        const bool rok = (unsigned)(h + kh - 2) < (unsigned)HDIM;
        const float* rp = zb + (kh * 5) * HW + (kh - 2) * WDIM;
        #pragma unroll
        for (int kw = 0; kw < 5; ++kw) {
            const float* tp = rp + kw * HW;
            float4 qa = (rok && cok0) ? *(const float4*)(tp - 4) : zf;
            float4 qb = (rok        ) ? *(const float4*)(tp)     : zf;
            float4 qc = (rok && cok2) ? *(const float4*)(tp + 4) : zf;
            float win[12] = {qa.x, qa.y, qa.z, qa.w, qb.x, qb.y, qb.z, qb.w,
                             qc.x, qc.y, qc.z, qc.w};
            s0 += win[kw + 2];
            s1 += win[kw + 3];
            s2 += win[kw + 4];
            s3 += win[kw + 5];
        }
    }
    float4 o = make_float4(s0, s1, s2, s3);
    *(float4*)(ak + (size_t)j * HW + px) = o;
}

// ---------------- fallback conv path (small-ws; proven round 5) ------------
__global__ __launch_bounds__(192) void k_conv(const float* __restrict__ x,
                                              const float* __restrict__ weffp,
                                              float* __restrict__ part) {
    const int j  = blockIdx.x;
    const int rt = blockIdx.y;
    const int g  = blockIdx.z;
    const int c0 = g * 16;
    __shared__ float tile[36 * 104];
    __shared__ float wsm[16 * WP];
    const int tid = threadIdx.x;
    for (int i = tid; i < 16 * WP; i += 192) wsm[i] = weffp[c0 * WP + i];
    const int cq = tid % 24;
    const int rg = tid / 24;
    const int r0 = rg * 4;
    const int rowbase = rt * 32;

    float4 acc[4];
    acc[0] = acc[1] = acc[2] = acc[3] = make_float4(0.f, 0.f, 0.f, 0.f);

    for (int ch = 0; ch < 16; ++ch) {
        const float* xc = x + (size_t)(j * CDIM + c0 + ch) * HW;
        __syncthreads();
        for (int idx = tid; idx < 36 * 26; idx += 192) {
            int r = idx / 26, q = idx % 26;
            int gr = rowbase - 2 + r;
            int gc = q * 4 - 4;
            float4 v = make_float4(0.f, 0.f, 0.f, 0.f);
            if (gr >= 0 && gr < HDIM && gc >= 0 && gc < WDIM)
                v = *(const float4*)(xc + gr * WDIM + gc);
            *(float4*)(tile + r * 104 + q * 4) = v;
        }
        __syncthreads();
        const float* wc = wsm + ch * WP;
        for (int rr = 0; rr < 8; ++rr) {
            const float* trow = tile + (r0 + rr) * 104 + cq * 4;
            float4 a  = *(const float4*)(trow);
            float4 b  = *(const float4*)(trow + 4);
            float4 c4 = *(const float4*)(trow + 8);
            float win[12] = {a.x, a.y, a.z, a.w, b.x, b.y, b.z, b.w,
                             c4.x, c4.y, c4.z, c4.w};
            #pragma unroll
            for (int orow = 0; orow < 4; ++orow) {
                int kh = rr - orow;
                if (kh < 0 || kh > 4) continue;
                #pragma unroll
                for (int kw = 0; kw < 5; ++kw) {
                    float w = wc[kh * 5 + kw];
                    acc[orow].x += w * win[kw + 2];
                    acc[orow].y += w * win[kw + 3];
                    acc[orow].z += w * win[kw + 4];
                    acc[orow].w += w * win[kw + 5];
                }
            }
        }
    }
    float* pr = part + (size_t)(g * 16 + j) * HW;
    #pragma unroll
    for (int orow = 0; orow < 4; ++orow) {
        int row = rowbase + r0 + orow;
        *(float4*)(pr + row * WDIM + cq * 4) = acc[orow];
    }
}

__global__ void k_combine(const float* __restrict__ part, float* __restrict__ ak) {
    const int j  = blockIdx.y;
    const int px = blockIdx.x * 256 + threadIdx.x;
    float s = 0.f;
    #pragma unroll
    for (int g = 0; g < 8; ++g) s += part[(size_t)(g * 16 + j) * HW + px];
    ak[(size_t)j * HW + px] = s;
}

// ---------------- K3: xbar[cp][px] = sum_j softmax_j(ak)[px] * x[j][cp][px] -
__global__ __launch_bounds__(256) void k_xbar(const float* __restrict__ x,
                                              const float* __restrict__ ak,
                                              float* __restrict__ xbar) {
    const int b  = blockIdx.x;
    const int cp = b / 9;
    const int px = (b % 9) * 1024 + threadIdx.x * 4;

    float4 av[16];
    #pragma unroll
    for (int j = 0; j < 16; ++j)
        av[j] = *(const float4*)(ak + (size_t)j * HW + px);

    float4 m = av[0];
    #pragma unroll
    for (int j = 1; j < 16; ++j) {
        m.x = fmaxf(m.x, av[j].x); m.y = fmaxf(m.y, av[j].y);
        m.z = fmaxf(m.z, av[j].z); m.w = fmaxf(m.w, av[j].w);
    }
    float4 tot = make_float4(0.f, 0.f, 0.f, 0.f);
    #pragma unroll
    for (int j = 0; j < 16; ++j) {
        av[j].x = __expf(av[j].x - m.x); av[j].y = __expf(av[j].y - m.y);
        av[j].z = __expf(av[j].z - m.z); av[j].w = __expf(av[j].w - m.w);
        tot.x += av[j].x; tot.y += av[j].y; tot.z += av[j].z; tot.w += av[j].w;
    }
    float4 inv = make_float4(1.f / tot.x, 1.f / tot.y, 1.f / tot.z, 1.f / tot.w);

    float4 acc = make_float4(0.f, 0.f, 0.f, 0.f);
    #pragma unroll
    for (int j = 0; j < 16; ++j) {
        float4 xv = *(const float4*)(x + (size_t)(j * CDIM + cp) * HW + px);
        fma4(acc, xv, av[j]);
    }
    acc.x *= inv.x; acc.y *= inv.y; acc.z *= inv.z; acc.w *= inv.w;
    *(float4*)(xbar + (size_t)cp * HW + px) = acc;
}

// ---------------- K4: out[i][c][px] = Wv*xbar + bv, 16x broadcast ----------
// grid (576, 2): c-split 2-way for occupancy; XCD-chunk px swizzle.
__global__ __launch_bounds__(256) void k_mat(const float* __restrict__ xbar,
                                             const float* __restrict__ wvt,
                                             const float* __restrict__ bv,
                                             float* __restrict__ out) {
    __shared__ float lx[128 * 16];
    const int b    = blockIdx.x;
    const int half = blockIdx.y;
    const int tile = (b & 7) * 72 + (b >> 3);   // 576 = 8 * 72
    const int px0  = tile * 16;
    const int tid  = threadIdx.x;

    #pragma unroll
    for (int i = 0; i < 2; ++i) {
        int lin = tid + i * 256;                // 0..511
        int cp = lin >> 2, q = lin & 3;
        *(float4*)(lx + cp * 16 + q * 4) =
            *(const float4*)(xbar + (size_t)cp * HW + px0 + q * 4);
    }
    __syncthreads();

    const int q = tid & 3;                      // px quad
    const int c = half * 64 + (tid >> 2);       // output channel
    float4 o = make_float4(0.f, 0.f, 0.f, 0.f);
    #pragma unroll 4
    for (int cp = 0; cp < 128; ++cp) {
        float4 xv = *(const float4*)(lx + cp * 16 + q * 4);
        axpy4(o, wvt[cp * 128 + c], xv);
    }
    float bb = bv[c];
    o.x += bb; o.y += bb; o.z += bb; o.w += bb;

    for (int i = 0; i < 16; ++i) {
        float* ob = out + (size_t)(i * CDIM + c) * HW + px0 + q * 4;
        *(float4*)(ob) = o;
    }
}

extern "C" void kernel_launch(void* const* d_in, const int* in_sizes, int n_in,
                              void* d_out, int out_size, void* d_ws, size_t ws_size,
                              hipStream_t stream) {
    const float* x  = (const float*)d_in[0];
    const float* Wk = (const float*)d_in[3];
    const float* Wv = (const float*)d_in[5];
    const float* bv = (const float*)d_in[6];
    const float* Wa = (const float*)d_in[7];
    float* out = (float*)d_out;

    char* ws = (char*)d_ws;
    float* weffp = (float*)(ws);            // 128*28*4 = 14,336 B
    float* wvt   = (float*)(ws + 16384);    // 64 KB, ends 81920

    k_prep<<<78, 256, 0, stream>>>(Wk, Wa, Wv, weffp, wvt);

    const size_t Z_BYTES  = (size_t)16 * 25 * HW * 4;   // 14.75 MB
    const size_t AK_BYTES = (size_t)16 * HW * 4;        // 590 KB
    const size_t NEED_BIG = 81920 + Z_BYTES + AK_BYTES; // 15.4 MB (proven fits)

    if (ws_size >= NEED_BIG) {
        float* z   = (float*)(ws + 81920);
        float* akb = (float*)(ws + 81920 + Z_BYTES);
        float* xb  = (float*)(ws + 81920);              // overlay: z dead after k_ak
        k_z   <<<dim3(36, 16),  256, 0, stream>>>(x, weffp, z);
        k_ak  <<<dim3(9, 16),   256, 0, stream>>>(z, akb);
        k_xbar<<<1152,          256, 0, stream>>>(x, akb, xb);
        k_mat <<<dim3(576, 2),  256, 0, stream>>>(xb, wvt, bv, out);
    } else {
        float* part = (float*)(ws + 81920);             // 4.72 MB
        float* akb  = (float*)(ws + 81920 + 4718592);   // 590 KB
        float* xb   = (float*)(ws + 81920);             // overlay: part dead
        k_conv   <<<dim3(16, 3, 8), 192, 0, stream>>>(x, weffp, part);
        k_combine<<<dim3(36, 16),   256, 0, stream>>>(part, akb);
        k_xbar   <<<1152,           256, 0, stream>>>(x, akb, xb);
        k_mat    <<<dim3(576, 2),   256, 0, stream>>>(xb, wvt, bv, out);
    }
}

// Round 20
// 73.864 us; speedup vs baseline: 1.2326x; 1.2326x over previous
//
#include <hip/hip_runtime.h>

// ConvAttention collapse:
//   softmax_j(Aq[i]+Ak[j]+ba) == softmax_j(Ak_linear[j])   (i-terms & biases cancel)
//   out[i] = Wv * (sum_j sm[j] * x[j]) + bv                (identical for all i)
// Pipeline: k_prep -> k_z (r12 structure: 4-wave c-split, s_load weights,
//           TWO-PASS 13.3KB LDS bounce -> 32 waves/CU) -> k_ak (4 px/thread)
//           -> k_xbar (softmax + weighted avg) -> k_mat (matvec + broadcast)

#define HW    9216      // 96*96
#define HDIM  96
#define WDIM  96
#define CDIM  128
#define WP    28        // padded taps per row (16B-aligned rows)

__device__ __forceinline__ void fma4(float4& a, const float4& x, const float4& s) {
    a.x += x.x * s.x; a.y += x.y * s.y; a.z += x.z * s.z; a.w += x.w * s.w;
}
__device__ __forceinline__ void axpy4(float4& o, float w, const float4& v) {
    o.x += w * v.x; o.y += w * v.y; o.z += w * v.z; o.w += w * v.w;
}

// ---------------- K0: prep — weffp padded (blocks 0..13) + Wv^T (14..77) --
// weffp[c'][tap] = sum_c Wk[c][c'] * Wa[(128+c)][tap], rows padded to 28.
__global__ void k_prep(const float* __restrict__ Wk, const float* __restrict__ Wa,
                       const float* __restrict__ Wv,
                       float* __restrict__ weffp, float* __restrict__ wvt) {
    const int b = blockIdx.x;
    if (b < 14) {
        int idx = b * 256 + threadIdx.x;
        if (idx < 128 * WP) {
            int cp = idx / WP, tap = idx % WP;
            float s = 0.f;
            if (tap < 25)
                for (int c = 0; c < 128; ++c)
                    s += Wk[c * 128 + cp] * Wa[(128 + c) * 25 + tap];
            weffp[idx] = s;
        }
    } else {
        int idx = (b - 14) * 256 + threadIdx.x;        // 0..16383
        wvt[(idx & 127) * 128 + (idx >> 7)] = Wv[idx]; // wvt[c'][c] = Wv[c][c']
    }
}

// ---------------- K1: z[j][t][hw] = sum_c weff[c][t] * x[j][c][hw] ---------
// Round-12 structure (best measured): block = 4 waves x 64 px; wave w owns
// channels [32w,32w+32); weights wave-uniform -> scalar s_load pipe.
// Cross-wave reduce via LDS bounce, SPLIT into two tap-halves so the
// buffer is 13.3 KB -> 8 blocks/CU (32 waves) instead of 6 (24 waves).
__global__ __launch_bounds__(256) void k_z(const float* __restrict__ x,
                                           const float* __restrict__ weffp,
                                           float* __restrict__ z) {
    __shared__ float red[4][13][64];   // 13.3 KB
    const int tid  = threadIdx.x;
    const int wav  = __builtin_amdgcn_readfirstlane(tid >> 6);
    const int lane = tid & 63;
    const int j    = blockIdx.y;
    const int px0  = blockIdx.x * 64;

    const float* wg = weffp + wav * 32 * WP;                       // uniform
    const float* xb = x + ((size_t)j * CDIM + wav * 32) * HW + px0 + lane;

    float acc[25];
    #pragma unroll
    for (int t = 0; t < 25; ++t) acc[t] = 0.f;

    #pragma unroll 4
    for (int c = 0; c < 32; ++c) {
        float xv = xb[(size_t)c * HW];
        #pragma unroll
        for (int t = 0; t < 25; ++t)
            acc[t] = fmaf(wg[c * WP + t], xv, acc[t]);   // weight from SGPR
    }

    float* zb = z + (size_t)j * 25 * HW + px0;

    // pass 1: taps 0..12
    #pragma unroll
    for (int t = 0; t < 13; ++t) red[wav][t][lane] = acc[t];
    __syncthreads();
    #pragma unroll
    for (int it = 0; it < 4; ++it) {
        int idx = it * 256 + tid;
        if (idx < 13 * 64) {
            int t = idx >> 6, p = idx & 63;
            zb[(size_t)t * HW + p] = (red[0][t][p] + red[1][t][p])
                                   + (red[2][t][p] + red[3][t][p]);
        }
    }
    __syncthreads();

    // pass 2: taps 13..24
    #pragma unroll
    for (int t = 0; t < 12; ++t) red[wav][t][lane] = acc[13 + t];
    __syncthreads();
    #pragma unroll
    for (int it = 0; it < 3; ++it) {
        int idx = it * 256 + tid;
        if (idx < 12 * 64) {
            int t = idx >> 6, p = idx & 63;
            zb[(size_t)(13 + t) * HW + p] = (red[0][t][p] + red[1][t][p])
                                          + (red[2][t][p] + red[3][t][p]);
        }
    }
}

// ---------------- K2: ak[j][px..px+3] via aligned 3-quad windows -----------
__global__ __launch_bounds__(256) void k_ak(const float* __restrict__ z,
                                            float* __restrict__ ak) {
    const int j  = blockIdx.y;
    const int px = (blockIdx.x * 256 + threadIdx.x) * 4;
    const int h  = px / WDIM, cb = px % WDIM;
    const bool cok0 = (cb > 0);
    const bool cok2 = (cb < WDIM - 4);
    const float4 zf = make_float4(0.f, 0.f, 0.f, 0.f);
    const float* zb = z + (size_t)j * 25 * HW + px;

    float s0 = 0.f, s1 = 0.f, s2 = 0.f, s3 = 0.f;
    #pragma unroll
    for (int kh = 0; kh < 5; ++kh) {
        const bool rok = (unsigned)(h + kh - 2) < (unsigned)HDIM;
        const float* rp = zb + (kh * 5) * HW + (kh - 2) * WDIM;
        #pragma unroll
        for (int kw = 0; kw < 5; ++kw) {
            const float* tp = rp + kw * HW;
            float4 qa = (rok && cok0) ? *(const float4*)(tp - 4) : zf;
            float4 qb = (rok        ) ? *(const float4*)(tp)     : zf;
            float4 qc = (rok && cok2) ? *(const float4*)(tp + 4) : zf;
            float win[12] = {qa.x, qa.y, qa.z, qa.w, qb.x, qb.y, qb.z, qb.w,
                             qc.x, qc.y, qc.z, qc.w};
            s0 += win[kw + 2];
            s1 += win[kw + 3];
            s2 += win[kw + 4];
            s3 += win[kw + 5];
        }
    }
    float4 o = make_float4(s0, s1, s2, s3);
    *(float4*)(ak + (size_t)j * HW + px) = o;
}

// ---------------- fallback conv path (small-ws; proven round 5) ------------
__global__ __launch_bounds__(192) void k_conv(const float* __restrict__ x,
                                              const float* __restrict__ weffp,
                                              float* __restrict__ part) {
    const int j  = blockIdx.x;
    const int rt = blockIdx.y;
    const int g  = blockIdx.z;
    const int c0 = g * 16;
    __shared__ float tile[36 * 104];
    __shared__ float wsm[16 * WP];
    const int tid = threadIdx.x;
    for (int i = tid; i < 16 * WP; i += 192) wsm[i] = weffp[c0 * WP + i];
    const int cq = tid % 24;
    const int rg = tid / 24;
    const int r0 = rg * 4;
    const int rowbase = rt * 32;

    float4 acc[4];
    acc[0] = acc[1] = acc[2] = acc[3] = make_float4(0.f, 0.f, 0.f, 0.f);

    for (int ch = 0; ch < 16; ++ch) {
        const float* xc = x + (size_t)(j * CDIM + c0 + ch) * HW;
        __syncthreads();
        for (int idx = tid; idx < 36 * 26; idx += 192) {
            int r = idx / 26, q = idx % 26;
            int gr = rowbase - 2 + r;
            int gc = q * 4 - 4;
            float4 v = make_float4(0.f, 0.f, 0.f, 0.f);
            if (gr >= 0 && gr < HDIM && gc >= 0 && gc < WDIM)
                v = *(const float4*)(xc + gr * WDIM + gc);
            *(float4*)(tile + r * 104 + q * 4) = v;
        }
        __syncthreads();
        const float* wc = wsm + ch * WP;
        for (int rr = 0; rr < 8; ++rr) {
            const float* trow = tile + (r0 + rr) * 104 + cq * 4;
            float4 a  = *(const float4*)(trow);
            float4 b  = *(const float4*)(trow + 4);
            float4 c4 = *(const float4*)(trow + 8);
            float win[12] = {a.x, a.y, a.z, a.w, b.x, b.y, b.z, b.w,
                             c4.x, c4.y, c4.z, c4.w};
            #pragma unroll
            for (int orow = 0; orow < 4; ++orow) {
                int kh = rr - orow;
                if (kh < 0 || kh > 4) continue;
                #pragma unroll
                for (int kw = 0; kw < 5; ++kw) {
                    float w = wc[kh * 5 + kw];
                    acc[orow].x += w * win[kw + 2];
                    acc[orow].y += w * win[kw + 3];
                    acc[orow].z += w * win[kw + 4];
                    acc[orow].w += w * win[kw + 5];
                }
            }
        }
    }
    float* pr = part + (size_t)(g * 16 + j) * HW;
    #pragma unroll
    for (int orow = 0; orow < 4; ++orow) {
        int row = rowbase + r0 + orow;
        *(float4*)(pr + row * WDIM + cq * 4) = acc[orow];
    }
}

__global__ void k_combine(const float* __restrict__ part, float* __restrict__ ak) {
    const int j  = blockIdx.y;
    const int px = blockIdx.x * 256 + threadIdx.x;
    float s = 0.f;
    #pragma unroll
    for (int g = 0; g < 8; ++g) s += part[(size_t)(g * 16 + j) * HW + px];
    ak[(size_t)j * HW + px] = s;
}

// ---------------- K3: xbar[cp][px] = sum_j softmax_j(ak)[px] * x[j][cp][px] -
__global__ __launch_bounds__(256) void k_xbar(const float* __restrict__ x,
                                              const float* __restrict__ ak,
                                              float* __restrict__ xbar) {
    const int b  = blockIdx.x;
    const int cp = b / 9;
    const int px = (b % 9) * 1024 + threadIdx.x * 4;

    float4 av[16];
    #pragma unroll
    for (int j = 0; j < 16; ++j)
        av[j] = *(const float4*)(ak + (size_t)j * HW + px);

    float4 m = av[0];
    #pragma unroll
    for (int j = 1; j < 16; ++j) {
        m.x = fmaxf(m.x, av[j].x); m.y = fmaxf(m.y, av[j].y);
        m.z = fmaxf(m.z, av[j].z); m.w = fmaxf(m.w, av[j].w);
    }
    float4 tot = make_float4(0.f, 0.f, 0.f, 0.f);
    #pragma unroll
    for (int j = 0; j < 16; ++j) {
        av[j].x = __expf(av[j].x - m.x); av[j].y = __expf(av[j].y - m.y);
        av[j].z = __expf(av[j].z - m.z); av[j].w = __expf(av[j].w - m.w);
        tot.x += av[j].x; tot.y += av[j].y; tot.z += av[j].z; tot.w += av[j].w;
    }
    float4 inv = make_float4(1.f / tot.x, 1.f / tot.y, 1.f / tot.z, 1.f / tot.w);

    float4 acc = make_float4(0.f, 0.f, 0.f, 0.f);
    #pragma unroll
    for (int j = 0; j < 16; ++j) {
        float4 xv = *(const float4*)(x + (size_t)(j * CDIM + cp) * HW + px);
        fma4(acc, xv, av[j]);
    }
    acc.x *= inv.x; acc.y *= inv.y; acc.z *= inv.z; acc.w *= inv.w;
    *(float4*)(xbar + (size_t)cp * HW + px) = acc;
}

// ---------------- K4: out[i][c][px] = Wv*xbar + bv, 16x broadcast ----------
// grid (576, 2): c-split 2-way for occupancy; XCD-chunk px swizzle.
__global__ __launch_bounds__(256) void k_mat(const float* __restrict__ xbar,
                                             const float* __restrict__ wvt,
                                             const float* __restrict__ bv,
                                             float* __restrict__ out) {
    __shared__ float lx[128 * 16];
    const int b    = blockIdx.x;
    const int half = blockIdx.y;
    const int tile = (b & 7) * 72 + (b >> 3);   // 576 = 8 * 72
    const int px0  = tile * 16;
    const int tid  = threadIdx.x;

    #pragma unroll
    for (int i = 0; i < 2; ++i) {
        int lin = tid + i * 256;                // 0..511
        int cp = lin >> 2, q = lin & 3;
        *(float4*)(lx + cp * 16 + q * 4) =
            *(const float4*)(xbar + (size_t)cp * HW + px0 + q * 4);
    }
    __syncthreads();

    const int q = tid & 3;                      // px quad
    const int c = half * 64 + (tid >> 2);       // output channel
    float4 o = make_float4(0.f, 0.f, 0.f, 0.f);
    #pragma unroll 4
    for (int cp = 0; cp < 128; ++cp) {
        float4 xv = *(const float4*)(lx + cp * 16 + q * 4);
        axpy4(o, wvt[cp * 128 + c], xv);
    }
    float bb = bv[c];
    o.x += bb; o.y += bb; o.z += bb; o.w += bb;

    for (int i = 0; i < 16; ++i) {
        float* ob = out + (size_t)(i * CDIM + c) * HW + px0 + q * 4;
        *(float4*)(ob) = o;
    }
}

extern "C" void kernel_launch(void* const* d_in, const int* in_sizes, int n_in,
                              void* d_out, int out_size, void* d_ws, size_t ws_size,
                              hipStream_t stream) {
    const float* x  = (const float*)d_in[0];
    const float* Wk = (const float*)d_in[3];
    const float* Wv = (const float*)d_in[5];
    const float* bv = (const float*)d_in[6];
    const float* Wa = (const float*)d_in[7];
    float* out = (float*)d_out;

    char* ws = (char*)d_ws;
    float* weffp = (float*)(ws);            // 128*28*4 = 14,336 B
    float* wvt   = (float*)(ws + 16384);    // 64 KB, ends 81920

    k_prep<<<78, 256, 0, stream>>>(Wk, Wa, Wv, weffp, wvt);

    const size_t Z_BYTES  = (size_t)16 * 25 * HW * 4;   // 14.75 MB
    const size_t AK_BYTES = (size_t)16 * HW * 4;        // 590 KB
    const size_t NEED_BIG = 81920 + Z_BYTES + AK_BYTES; // 15.4 MB (proven fits)

    if (ws_size >= NEED_BIG) {
        float* z   = (float*)(ws + 81920);
        float* akb = (float*)(ws + 81920 + Z_BYTES);
        float* xb  = (float*)(ws + 81920);              // overlay: z dead after k_ak
        k_z   <<<dim3(144, 16), 256, 0, stream>>>(x, weffp, z);
        k_ak  <<<dim3(9, 16),   256, 0, stream>>>(z, akb);
        k_xbar<<<1152,          256, 0, stream>>>(x, akb, xb);
        k_mat <<<dim3(576, 2),  256, 0, stream>>>(xb, wvt, bv, out);
    } else {
        float* part = (float*)(ws + 81920);             // 4.72 MB
        float* akb  = (float*)(ws + 81920 + 4718592);   // 590 KB
        float* xb   = (float*)(ws + 81920);             // overlay: part dead
        k_conv   <<<dim3(16, 3, 8), 192, 0, stream>>>(x, weffp, part);
        k_combine<<<dim3(36, 16),   256, 0, stream>>>(part, akb);
        k_xbar   <<<1152,           256, 0, stream>>>(x, akb, xb);
        k_mat    <<<dim3(576, 2),   256, 0, stream>>>(xb, wvt, bv, out);
    }
}